// Round 2
// baseline (116.093 us; speedup 1.0000x reference)
//
#include <hip/hip_runtime.h>
#include <math.h>

#define NHEADS 8
#define KD 16
#define EMBED 128
#define BATCH 32
#define NSEQ 16384
#define NCHUNK 64
#define CHUNK (NSEQ / NCHUNK)   // 256 rows per chunk
#define PART_STRIDE 18          // m, l, acc[16]

// Kernel 1: per-(batch, chunk) online-softmax partials over all 8 heads.
// Layout: lane = 32*half + lc. Lane covers dims [4*lc, 4*lc+3] (float4).
// Lanes 0-31 process even rows, lanes 32-63 odd rows -> one float4 load
// instruction covers 2 full 512B rows (64 lanes x 16B = 1KiB), and the
// two halves run independent online-softmax chains (2x ILP), merged at end.
__global__ __launch_bounds__(256) void attn_partial(
    const float* __restrict__ q,
    const float* __restrict__ K,
    const float* __restrict__ V,
    const float* __restrict__ mask,
    float* __restrict__ part)
{
    const int b    = blockIdx.x >> 6;      // NCHUNK == 64
    const int c    = blockIdx.x & 63;
    const int wave = threadIdx.x >> 6;
    const int lane = threadIdx.x & 63;
    const int half = lane >> 5;            // row parity
    const int lc   = lane & 31;            // column lane within row
    const int head = lc >> 2;              // 4 lanes per head
    const int g    = lc & 3;               // dim group within head

    const float4 q4 = *(const float4*)&q[b * EMBED + 4 * lc];

    const size_t rowbase = (size_t)b * NSEQ;
    const int rw = c * CHUNK + wave * 64;  // this wave's 64-row sub-chunk

    // Prefetch this wave's 64 mask values into one register per lane.
    const float mv = mask[rowbase + rw + lane];

    float m = -INFINITY;
    float lsum = 0.f;
    float4 acc = {0.f, 0.f, 0.f, 0.f};

    #pragma unroll 4
    for (int i = 0; i < 32; ++i) {
        const int row = rw + 2 * i + half;
        const size_t off = (rowbase + row) * EMBED + 4 * lc;
        const float4 k4 = *(const float4*)&K[off];
        const float4 v4 = *(const float4*)&V[off];
        float p = q4.x * k4.x + q4.y * k4.y + q4.z * k4.z + q4.w * k4.w;
        p += __shfl_xor(p, 1);
        p += __shfl_xor(p, 2);
        const float s  = p * 0.25f + __shfl(mv, 2 * i + half);  // scale = 1/sqrt(16)
        const float mn = fmaxf(m, s);
        const float corr = __expf(m - mn);
        const float w    = __expf(s - mn);
        lsum  = lsum  * corr + w;
        acc.x = acc.x * corr + w * v4.x;
        acc.y = acc.y * corr + w * v4.y;
        acc.z = acc.z * corr + w * v4.z;
        acc.w = acc.w * corr + w * v4.w;
        m = mn;
    }

    // 8 partial sets per block: (wave, half). Merge via LDS.
    __shared__ float lds[8][NHEADS][PART_STRIDE];
    const int set = wave * 2 + half;
    float* dst = lds[set][head];
    dst[2 + 4 * g + 0] = acc.x;
    dst[2 + 4 * g + 1] = acc.y;
    dst[2 + 4 * g + 2] = acc.z;
    dst[2 + 4 * g + 3] = acc.w;
    if (g == 0) { dst[0] = m; dst[1] = lsum; }
    __syncthreads();

    const int t = threadIdx.x;
    if (t < EMBED) {
        const int h = t >> 4;
        const int d = t & 15;
        float M = -INFINITY;
        #pragma unroll
        for (int s8 = 0; s8 < 8; ++s8) M = fmaxf(M, lds[s8][h][0]);
        float L = 0.f, A = 0.f;
        #pragma unroll
        for (int s8 = 0; s8 < 8; ++s8) {
            const float e = __expf(lds[s8][h][0] - M);
            L += lds[s8][h][1] * e;
            A += lds[s8][h][2 + d] * e;
        }
        float* p = &part[((size_t)(b * NCHUNK + c) * NHEADS + h) * PART_STRIDE];
        p[2 + d] = A;
        if (d == 0) { p[0] = M; p[1] = L; }
    }
}

// Kernel 2: merge chunk partials, normalize, apply W_out projection.
__global__ __launch_bounds__(128) void attn_finish(
    const float* __restrict__ part,
    const float* __restrict__ Wout,
    float* __restrict__ out)
{
    const int b = blockIdx.x;
    const int t = threadIdx.x;
    const int h = t >> 4;
    const int d = t & 15;

    __shared__ float heads[EMBED];

    float M = -INFINITY, L = 0.f, A = 0.f;
    for (int c = 0; c < NCHUNK; ++c) {
        const float* p = &part[((size_t)(b * NCHUNK + c) * NHEADS + h) * PART_STRIDE];
        const float mc = p[0];
        const float Mn = fmaxf(M, mc);
        const float eM = __expf(M - Mn);
        const float ec = __expf(mc - Mn);
        L = L * eM + p[1] * ec;
        A = A * eM + p[2 + d] * ec;
        M = Mn;
    }
    heads[t] = A / L;
    __syncthreads();

    float o = 0.f;
    #pragma unroll 8
    for (int dd = 0; dd < EMBED; ++dd)
        o += heads[dd] * Wout[dd * EMBED + t];
    out[b * EMBED + t] = o;
}

extern "C" void kernel_launch(void* const* d_in, const int* in_sizes, int n_in,
                              void* d_out, int out_size, void* d_ws, size_t ws_size,
                              hipStream_t stream) {
    const float* q    = (const float*)d_in[0];
    const float* K    = (const float*)d_in[1];
    const float* V    = (const float*)d_in[2];
    const float* mask = (const float*)d_in[3];
    const float* Wout = (const float*)d_in[4];
    float* out  = (float*)d_out;
    float* part = (float*)d_ws;   // BATCH*NCHUNK*NHEADS*18 floats ≈ 1.13 MB

    attn_partial<<<BATCH * NCHUNK, 256, 0, stream>>>(q, K, V, mask, part);
    attn_finish<<<BATCH, 128, 0, stream>>>(part, Wout, out);
}

// Round 4
// 89.773 us; speedup vs baseline: 1.2932x; 1.2932x over previous
//
#include <hip/hip_runtime.h>
#include <math.h>

#define NHEADS 8
#define KD 16
#define EMBED 128
#define BATCH 32
#define NSEQ 16384
#define NCHUNK 64
#define CHUNK (NSEQ / NCHUNK)   // 256 rows per chunk
#define PART_STRIDE 18          // m, l, acc[16]

typedef float f32x2 __attribute__((ext_vector_type(2)));

// Kernel 1: per-(batch, chunk) online-softmax partials over all 8 heads.
// Each wave reads whole 128-float rows: lane l covers dims [2l, 2l+1],
// head = lane>>3 (8 lanes per head, 16 dims per head).
// K/V are read-once streams -> nontemporal loads (no cache allocate).
__global__ __launch_bounds__(256) void attn_partial(
    const float* __restrict__ q,
    const float* __restrict__ K,
    const float* __restrict__ V,
    const float* __restrict__ mask,
    float* __restrict__ part)
{
    const int b    = blockIdx.x >> 6;      // NCHUNK == 64
    const int c    = blockIdx.x & 63;
    const int wave = threadIdx.x >> 6;
    const int lane = threadIdx.x & 63;
    const int head = lane >> 3;
    const int g    = lane & 7;             // position within head group

    const f32x2 q2 = *(const f32x2*)&q[b * EMBED + 2 * lane];

    float m = -INFINITY;
    float lsum = 0.f;
    float accx = 0.f, accy = 0.f;

    const size_t rowbase = (size_t)b * NSEQ;
    const int r0 = c * CHUNK;

    #pragma unroll 4
    for (int r = r0 + wave; r < r0 + CHUNK; r += 4) {
        const size_t off = (rowbase + r) * EMBED + 2 * lane;
        const f32x2 k2 = __builtin_nontemporal_load((const f32x2*)&K[off]);
        const f32x2 v2 = __builtin_nontemporal_load((const f32x2*)&V[off]);
        float p = q2.x * k2.x + q2.y * k2.y;
        p += __shfl_xor(p, 1);
        p += __shfl_xor(p, 2);
        p += __shfl_xor(p, 4);
        const float s  = p * 0.25f + mask[rowbase + r];   // scale = 1/sqrt(16)
        const float mn = fmaxf(m, s);
        const float corr = __expf(m - mn);
        const float w    = __expf(s - mn);
        lsum = lsum * corr + w;
        accx = accx * corr + w * v2.x;
        accy = accy * corr + w * v2.y;
        m = mn;
    }

    // Combine the 4 waves' partials via LDS.
    __shared__ float lds[4][NHEADS][PART_STRIDE];
    lds[wave][head][2 + 2 * g]     = accx;
    lds[wave][head][2 + 2 * g + 1] = accy;
    if (g == 0) {
        lds[wave][head][0] = m;
        lds[wave][head][1] = lsum;
    }
    __syncthreads();

    const int t = threadIdx.x;
    if (t < EMBED) {
        const int h = t >> 4;
        const int d = t & 15;
        float M = -INFINITY;
        #pragma unroll
        for (int w = 0; w < 4; ++w) M = fmaxf(M, lds[w][h][0]);
        float L = 0.f, A = 0.f;
        #pragma unroll
        for (int w = 0; w < 4; ++w) {
            const float e = __expf(lds[w][h][0] - M);
            L += lds[w][h][1] * e;
            A += lds[w][h][2 + d] * e;
        }
        float* p = &part[((size_t)(b * NCHUNK + c) * NHEADS + h) * PART_STRIDE];
        p[2 + d] = A;
        if (d == 0) { p[0] = M; p[1] = L; }
    }
}

// Kernel 2: merge chunk partials (4 independent chains -> 4x less serial
// latency), normalize, apply W_out projection.
__global__ __launch_bounds__(128) void attn_finish(
    const float* __restrict__ part,
    const float* __restrict__ Wout,
    float* __restrict__ out)
{
    const int b = blockIdx.x;
    const int t = threadIdx.x;
    const int h = t >> 4;
    const int d = t & 15;

    __shared__ float heads[EMBED];

    float Mc[4], Lc[4], Ac[4];
    #pragma unroll
    for (int j = 0; j < 4; ++j) { Mc[j] = -INFINITY; Lc[j] = 0.f; Ac[j] = 0.f; }

    #pragma unroll 4
    for (int i = 0; i < 16; ++i) {
        #pragma unroll
        for (int j = 0; j < 4; ++j) {
            const int c = j * 16 + i;
            const float* p = &part[((size_t)(b * NCHUNK + c) * NHEADS + h) * PART_STRIDE];
            const float mc = p[0];
            const float lc = p[1];
            const float ac = p[2 + d];
            const float Mn = fmaxf(Mc[j], mc);
            const float eM = __expf(Mc[j] - Mn);
            const float ec = __expf(mc - Mn);
            Lc[j] = Lc[j] * eM + lc * ec;
            Ac[j] = Ac[j] * eM + ac * ec;
            Mc[j] = Mn;
        }
    }

    const float M = fmaxf(fmaxf(Mc[0], Mc[1]), fmaxf(Mc[2], Mc[3]));
    float L = 0.f, A = 0.f;
    #pragma unroll
    for (int j = 0; j < 4; ++j) {
        const float e = __expf(Mc[j] - M);
        L += Lc[j] * e;
        A += Ac[j] * e;
    }
    heads[t] = A / L;
    __syncthreads();

    float o = 0.f;
    #pragma unroll 8
    for (int dd = 0; dd < EMBED; ++dd)
        o += heads[dd] * Wout[dd * EMBED + t];
    out[b * EMBED + t] = o;
}

extern "C" void kernel_launch(void* const* d_in, const int* in_sizes, int n_in,
                              void* d_out, int out_size, void* d_ws, size_t ws_size,
                              hipStream_t stream) {
    const float* q    = (const float*)d_in[0];
    const float* K    = (const float*)d_in[1];
    const float* V    = (const float*)d_in[2];
    const float* mask = (const float*)d_in[3];
    const float* Wout = (const float*)d_in[4];
    float* out  = (float*)d_out;
    float* part = (float*)d_ws;   // BATCH*NCHUNK*NHEADS*18 floats ≈ 1.13 MB

    attn_partial<<<BATCH * NCHUNK, 256, 0, stream>>>(q, K, V, mask, part);
    attn_finish<<<BATCH, 128, 0, stream>>>(part, Wout, out);
}